// Round 1
// baseline (439.450 us; speedup 1.0000x reference)
//
#include <hip/hip_runtime.h>
#include <math.h>

#define BB    1024
#define FF    1024
#define NOUT  512
#define NW    256
#define RT    64     // rows per block (= lanes per wave)
#define CT    32     // cols per block (4 waves x 8 cols)
#define CW    8      // cols per lane
#define KT    64     // K chunk staged in LDS
#define NTILE 256    // (NOUT/CT) * (BB/RT) output tiles

__device__ int g_cnt[NTILE];   // .bss -> zero at load; monotonic tickets

template<bool ERO>
__device__ __forceinline__ void trop_core(
    float (* __restrict__ lds_x)[RT],
    const float* __restrict__ x,
    const float* __restrict__ w,
    float* __restrict__ out,
    float* __restrict__ ws,
    const int c0w, const int cout0, const int ks, const int ch)
{
    const int tid  = threadIdx.x;
    const int lane = tid & 63;          // = row within tile
    const int wv   = tid >> 6;          // wave -> col group
    const int by   = blockIdx.y;
    const int bz   = blockIdx.z;
    const int r0   = by * RT;
    const int cw0  = c0w + wv * CW;     // col base inside weight matrix

    float acc[CW];
#pragma unroll
    for (int j = 0; j < CW; ++j) acc[j] = -INFINITY;

    const int fstart = bz * ch;
    const int nchunk = ch / KT;

    for (int kc = 0; kc < nchunk; ++kc) {
        const int fb = fstart + kc * KT;
        if (kc) __syncthreads();
        // ---- stage x^T chunk: lds_x[k][row ^ (k&60)] (swizzle: <=2-way banks) ----
#pragma unroll
        for (int q = 0; q < 4; ++q) {
            const int idx = tid + q * 256;
            const int r   = idx >> 4;            // 0..63
            const int kq  = (idx & 15) << 2;     // 0,4,...,60 (group base)
            const float4 v = *(const float4*)(x + (size_t)(r0 + r) * FF + fb + kq);
            const int cs = r ^ kq;               // kq == ((kq>>2)&15)<<2
            lds_x[kq + 0][cs] = v.x;
            lds_x[kq + 1][cs] = v.y;
            lds_x[kq + 2][cs] = v.z;
            lds_x[kq + 3][cs] = v.w;
        }
        __syncthreads();

        // ---- inner: w wave-uniform (SGPR), x per-lane (ds_read2), max3 fuse ----
#pragma unroll 4
        for (int k = 0; k < KT; k += 2) {
            const float* wr = w + (size_t)(fb + k) * NW + cw0;
            const int cs = lane ^ (k & 60);
            const float x0 = lds_x[k][cs];
            const float x1 = lds_x[k + 1][cs];
            const float4 wa = *(const float4*)(wr);
            const float4 wb = *(const float4*)(wr + 4);
            const float4 wc = *(const float4*)(wr + NW);
            const float4 wd = *(const float4*)(wr + NW + 4);
            const float w0[8] = {wa.x, wa.y, wa.z, wa.w, wb.x, wb.y, wb.z, wb.w};
            const float w1[8] = {wc.x, wc.y, wc.z, wc.w, wd.x, wd.y, wd.z, wd.w};
#pragma unroll
            for (int j = 0; j < CW; ++j) {
                const float t0 = ERO ? (w0[j] - x0) : (x0 + w0[j]);
                const float t1 = ERO ? (w1[j] - x1) : (x1 + w1[j]);
                acc[j] = fmaxf(acc[j], fmaxf(t0, t1));
            }
        }
    }

    // ---- bias row f=FF: x contribution 0 -> just the weight ----
    if (bz == ks - 1) {
        const float* wbias = w + (size_t)FF * NW + cw0;
        const float4 ba = *(const float4*)(wbias);
        const float4 bb = *(const float4*)(wbias + 4);
        const float bc[8] = {ba.x, ba.y, ba.z, ba.w, bb.x, bb.y, bb.z, bb.w};
#pragma unroll
        for (int j = 0; j < CW; ++j) acc[j] = fmaxf(acc[j], bc[j]);
    }

    const int row  = r0 + lane;
    const int cout = cout0 + wv * CW;

    float res[CW];
#pragma unroll
    for (int j = 0; j < CW; ++j) res[j] = ERO ? -acc[j] : acc[j];

    if (ks == 1) {
        float4 v0 = {res[0], res[1], res[2], res[3]};
        float4 v1 = {res[4], res[5], res[6], res[7]};
        *(float4*)(out + (size_t)row * NOUT + cout)     = v0;
        *(float4*)(out + (size_t)row * NOUT + cout + 4) = v1;
        return;
    }

    // ---- write partial slice ----
    {
        float4 v0 = {res[0], res[1], res[2], res[3]};
        float4 v1 = {res[4], res[5], res[6], res[7]};
        float* p = ws + (size_t)bz * (BB * NOUT) + (size_t)row * NOUT + cout;
        *(float4*)p       = v0;
        *(float4*)(p + 4) = v1;
    }

    // ---- last-arrival block of this tile combines all ks slices ----
    __threadfence();                       // release partials (device scope)
    __shared__ int s_last;
    if (tid == 0) {
        const int tile = by * gridDim.x + blockIdx.x;
        const int old = atomicAdd(&g_cnt[tile], 1);
        s_last = (((old + 1) & (ks - 1)) == 0) ? 1 : 0;   // ks is pow2
    }
    __syncthreads();
    if (!s_last) return;
    __threadfence();                       // acquire others' partials

    for (int z = 0; z < ks; ++z) {
        if (z == bz) continue;
        const float* p = ws + (size_t)z * (BB * NOUT) + (size_t)row * NOUT + cout;
        const float4 u0 = *(const float4*)p;
        const float4 u1 = *(const float4*)(p + 4);
        const float u[8] = {u0.x, u0.y, u0.z, u0.w, u1.x, u1.y, u1.z, u1.w};
#pragma unroll
        for (int j = 0; j < CW; ++j)
            res[j] = ERO ? fminf(res[j], u[j]) : fmaxf(res[j], u[j]);
    }
    float4 v0 = {res[0], res[1], res[2], res[3]};
    float4 v1 = {res[4], res[5], res[6], res[7]};
    *(float4*)(out + (size_t)row * NOUT + cout)     = v0;
    *(float4*)(out + (size_t)row * NOUT + cout + 4) = v1;
}

__global__ __launch_bounds__(256, 8) void trop_main(
    const float* __restrict__ x,
    const float* __restrict__ dil,
    const float* __restrict__ ero,
    float* __restrict__ out,
    float* __restrict__ ws,
    const int ks, const int ch)
{
    __shared__ float lds_x[KT][RT];
    const int bx = blockIdx.x;
    if (bx < NW / CT) {
        trop_core<true >(lds_x, x, ero, out, ws, bx * CT,      bx * CT, ks, ch);
    } else {
        trop_core<false>(lds_x, x, dil, out, ws, bx * CT - NW, bx * CT, ks, ch);
    }
}

extern "C" void kernel_launch(void* const* d_in, const int* in_sizes, int n_in,
                              void* d_out, int out_size, void* d_ws, size_t ws_size,
                              hipStream_t stream) {
    const float* x   = (const float*)d_in[0];
    const float* dil = (const float*)d_in[1];
    const float* ero = (const float*)d_in[2];
    float* out = (float*)d_out;

    const size_t outbytes = (size_t)BB * NOUT * sizeof(float);
    int ks = 1;
    if      (ws_size >= 8 * outbytes) ks = 8;
    else if (ws_size >= 4 * outbytes) ks = 4;
    else if (ws_size >= 2 * outbytes) ks = 2;

    dim3 grid(NOUT / CT, BB / RT, ks);
    trop_main<<<grid, 256, 0, stream>>>(x, dil, ero, out, (float*)d_ws, ks, FF / ks);
}

// Round 2
// 209.892 us; speedup vs baseline: 2.0937x; 2.0937x over previous
//
#include <hip/hip_runtime.h>
#include <math.h>

#define BB   1024
#define FF   1024
#define NOUT 512
#define NW   256
#define RT   8      // rows per thread (= rows per block)
#define KC   4      // k software-pipeline chunk
#define NTILE 256   // 128 row-blocks x 2 col-halves

typedef float f4 __attribute__((ext_vector_type(4)));

__device__ int g_cnt[NTILE];   // .bss zeroed at load; monotonic tickets mod ks

template<bool ERO>
__device__ __forceinline__ void core(
    const float* __restrict__ x,
    const float* __restrict__ w,
    float* __restrict__ out,
    float* __restrict__ ws,
    const int ks, const int ch)
{
    const int tid  = threadIdx.x;      // column within the 256-col half
    const int by   = blockIdx.y;
    const int bz   = blockIdx.z;
    const int row0 = by * RT;
    const int fstart = bz * ch;
    const int fend   = fstart + ch;
    const float* __restrict__ wcol = w + tid;   // per-lane column base (coalesced)

    float acc[RT];
#pragma unroll
    for (int r = 0; r < RT; ++r) acc[r] = -INFINITY;

    f4    xA[RT], xB[RT];   // x chunk: BLOCK-uniform addresses -> s_load
    float wA[KC], wB[KC];   // w chunk: per-lane coalesced b32

    auto loadx = [&](f4* xr, const int kg) {
#pragma unroll
        for (int r = 0; r < RT; ++r)
            xr[r] = *(const f4*)(x + (size_t)(row0 + r) * FF + kg);
    };
    auto loadw = [&](float* wr, const int kg) {
#pragma unroll
        for (int k = 0; k < KC; ++k)
            wr[k] = wcol[(size_t)(kg + k) * NW];
    };
    auto compute = [&](const f4* xr, const float* wr) {
#pragma unroll
        for (int k = 0; k < KC; k += 2) {
#pragma unroll
            for (int r = 0; r < RT; ++r) {
                const float x0 = xr[r][k];
                const float x1 = xr[r][k + 1];
                const float t0 = ERO ? (wr[k]     - x0) : (x0 + wr[k]);
                const float t1 = ERO ? (wr[k + 1] - x1) : (x1 + wr[k + 1]);
                acc[r] = fmaxf(acc[r], fmaxf(t0, t1));   // -> v_max3_f32
            }
        }
    };

    // prologue
    loadx(xA, fstart);
    loadw(wA, fstart);

    for (int kb = 0; kb < ch; kb += 2 * KC) {
        const int kgB = fstart + kb + KC;          // always < fend
        loadx(xB, kgB);
        loadw(wB, kgB);
        compute(xA, wA);

        const int kn  = fstart + kb + 2 * KC;
        const int kgA = (kn < fend) ? kn : fstart; // clamp: harmless reload on last iter
        loadx(xA, kgA);
        loadw(wA, kgA);
        compute(xB, wB);
    }

    // bias row f=FF: x contribution is 0 -> just the weight value
    if (bz == ks - 1) {
        const float wb = wcol[(size_t)FF * NW];
#pragma unroll
        for (int r = 0; r < RT; ++r) acc[r] = fmaxf(acc[r], wb);
    }

    float res[RT];
#pragma unroll
    for (int r = 0; r < RT; ++r) res[r] = ERO ? -acc[r] : acc[r];

    const int col = (ERO ? 0 : NW) + tid;

    if (ks == 1) {
#pragma unroll
        for (int r = 0; r < RT; ++r)
            out[(size_t)(row0 + r) * NOUT + col] = res[r];
        return;
    }

    // write this K-slice's partial
    {
        float* p = ws + (size_t)bz * (BB * NOUT);
#pragma unroll
        for (int r = 0; r < RT; ++r)
            p[(size_t)(row0 + r) * NOUT + col] = res[r];
    }

    // last-arrival block of this tile reduces all ks slices (fused combine)
    __threadfence();                     // release partials (device scope)
    __shared__ int s_last;
    if (tid == 0) {
        const int tile = by * 2 + (ERO ? 0 : 1);
        const int old = atomicAdd(&g_cnt[tile], 1);
        s_last = (((old + 1) & (ks - 1)) == 0) ? 1 : 0;   // ks is pow2
    }
    __syncthreads();
    if (!s_last) return;
    __threadfence();                     // acquire others' partials

    for (int z = 0; z < ks; ++z) {
        if (z == bz) continue;
        const float* p = ws + (size_t)z * (BB * NOUT);
#pragma unroll
        for (int r = 0; r < RT; ++r) {
            const float u = p[(size_t)(row0 + r) * NOUT + col];
            res[r] = ERO ? fminf(res[r], u) : fmaxf(res[r], u);
        }
    }
#pragma unroll
    for (int r = 0; r < RT; ++r)
        out[(size_t)(row0 + r) * NOUT + col] = res[r];
}

__global__ __launch_bounds__(256, 4) void trop_main(
    const float* __restrict__ x,
    const float* __restrict__ dil,
    const float* __restrict__ ero,
    float* __restrict__ out,
    float* __restrict__ ws,
    const int ks, const int ch)
{
    if (blockIdx.x == 0) core<true >(x, ero, out, ws, ks, ch);
    else                 core<false>(x, dil, out, ws, ks, ch);
}

extern "C" void kernel_launch(void* const* d_in, const int* in_sizes, int n_in,
                              void* d_out, int out_size, void* d_ws, size_t ws_size,
                              hipStream_t stream) {
    const float* x   = (const float*)d_in[0];
    const float* dil = (const float*)d_in[1];
    const float* ero = (const float*)d_in[2];
    float* out = (float*)d_out;

    const size_t outbytes = (size_t)BB * NOUT * sizeof(float);
    int ks = 1;
    if      (ws_size >= 4 * outbytes) ks = 4;
    else if (ws_size >= 2 * outbytes) ks = 2;

    dim3 grid(2, BB / RT, ks);
    trop_main<<<grid, 256, 0, stream>>>(x, dil, ero, out, (float*)d_ws, ks, FF / ks);
}